// Round 2
// baseline (6507.437 us; speedup 1.0000x reference)
//
#include <hip/hip_runtime.h>
#include <hip/hip_bf16.h>

typedef unsigned short u16;
typedef unsigned int u32;

// ---------------- constants ----------------
#define BATCH 2
#define NSEQ  4096
#define DIM   1024
#define HEADS 16
#define DH    64
#define WIN   512
#define INNER 2730
#define ROWS  (BATCH * NSEQ)          // 8192
#define QKV_N (3 * HEADS * DH)        // 3072
#define FF1_N (2 * INNER)             // 5460

// ---------------- helpers ----------------
__device__ __forceinline__ float bf2f(u16 u) {
    union { u32 i; float f; } c; c.i = ((u32)u) << 16; return c.f;
}
__device__ __forceinline__ u16 f2bf(float f) {
    union { float f; u32 i; } c; c.f = f;
    u32 i = c.i;
    u32 r = (i + 0x7FFFu + ((i >> 16) & 1u)) >> 16;   // RNE
    return (u16)r;
}

typedef __attribute__((ext_vector_type(8))) short short8;
typedef __attribute__((ext_vector_type(4))) float float4v;

// ---------------- fp32 -> bf16 cast ----------------
__global__ __launch_bounds__(256) void f2b_kernel(const float* __restrict__ in,
                                                  u16* __restrict__ out, int n) {
    int i = blockIdx.x * 256 + threadIdx.x;
    if (i < n) out[i] = f2bf(in[i]);
}

// ---------------- LayerNorm: fp32 in, bf16 out (dim = 1024) ----------------
__global__ __launch_bounds__(256) void ln_kernel(const float* __restrict__ x,
                                                 const float* __restrict__ w,
                                                 const float* __restrict__ b,
                                                 u16* __restrict__ out) {
    int row = blockIdx.x;
    const float* xr = x + (size_t)row * DIM;
    int t = threadIdx.x;
    float v[4];
    float s = 0.f, s2 = 0.f;
#pragma unroll
    for (int i = 0; i < 4; i++) {
        float f = xr[t + 256 * i];
        v[i] = f; s += f; s2 += f * f;
    }
#pragma unroll
    for (int off = 32; off; off >>= 1) {
        s  += __shfl_xor(s,  off);
        s2 += __shfl_xor(s2, off);
    }
    __shared__ float ls[10];
    int wave = t >> 6, lane = t & 63;
    if (lane == 0) { ls[wave] = s; ls[4 + wave] = s2; }
    __syncthreads();
    if (t == 0) {
        float ts  = ls[0] + ls[1] + ls[2] + ls[3];
        float ts2 = ls[4] + ls[5] + ls[6] + ls[7];
        float mean = ts * (1.f / DIM);
        float var  = ts2 * (1.f / DIM) - mean * mean;
        ls[8] = mean;
        ls[9] = 1.f / sqrtf(var + 1e-5f);
    }
    __syncthreads();
    float mean = ls[8], inv = ls[9];
    u16* orow = out + (size_t)row * DIM;
#pragma unroll
    for (int i = 0; i < 4; i++) {
        int c = t + 256 * i;
        float y = (v[i] - mean) * inv * w[c];
        if (b) y += b[c];
        orow[c] = f2bf(y);
    }
}

// ---------------- GEMM: C[M,N] = A[M,K] @ B[K,N] (+fp32 resid) ----------------
// A,B bf16. F32OUT: C fp32 (+resid fp32). else: C bf16, no resid.
// one wave -> one 16x16 C tile via mfma_f32_16x16x32_bf16
template <bool F32OUT>
__global__ __launch_bounds__(256) void gemm_kernel(const u16* __restrict__ A,
                                                   const u16* __restrict__ Bm,
                                                   const float* __restrict__ resid,
                                                   void* __restrict__ Cv,
                                                   int M, int N, int K) {
    int tiles_n = (N + 15) >> 4;
    int wave = threadIdx.x >> 6;
    int lane = threadIdx.x & 63;
    long tile = (long)blockIdx.x * 4 + wave;
    int tm = (int)(tile / tiles_n);
    int tn = (int)(tile % tiles_n);
    if (tm * 16 >= M) return;
    int quad = lane >> 4;
    int lrow = lane & 15;
    int arow = tm * 16 + lrow;
    int bcol = tn * 16 + lrow;
    bool colok = (bcol < N);
    const u16* Arow = A + (size_t)arow * K;
    float4v acc = {0.f, 0.f, 0.f, 0.f};
    int kfull = K & ~31;
    for (int k0 = 0; k0 < kfull; k0 += 32) {
        int kb = k0 + quad * 8;
        union { u32 u[4]; short8 s; } ua;   // 4B-aligned loads (K even)
        const u32* ap = (const u32*)(Arow + kb);
        ua.u[0] = ap[0]; ua.u[1] = ap[1]; ua.u[2] = ap[2]; ua.u[3] = ap[3];
        short8 bfr;
#pragma unroll
        for (int j = 0; j < 8; j++)
            bfr[j] = colok ? (short)Bm[(size_t)(kb + j) * N + bcol] : (short)0;
        acc = __builtin_amdgcn_mfma_f32_16x16x32_bf16(ua.s, bfr, acc, 0, 0, 0);
    }
    if (kfull < K) {
        int kb = kfull + quad * 8;
        short8 afr, bfr;
#pragma unroll
        for (int j = 0; j < 8; j++) {
            int k = kb + j;
            afr[j] = (k < K) ? (short)Arow[k] : (short)0;
            bfr[j] = (k < K && colok) ? (short)Bm[(size_t)k * N + bcol] : (short)0;
        }
        acc = __builtin_amdgcn_mfma_f32_16x16x32_bf16(afr, bfr, acc, 0, 0, 0);
    }
#pragma unroll
    for (int r = 0; r < 4; r++) {
        int row = tm * 16 + quad * 4 + r;
        if (colok) {
            size_t idx = (size_t)row * N + bcol;
            if (F32OUT) {
                float vv = acc[r];
                if (resid) vv += resid[idx];
                ((float*)Cv)[idx] = vv;
            } else {
                ((u16*)Cv)[idx] = f2bf(acc[r]);
            }
        }
    }
}

// ---------------- rotary (in-place on bf16 qkv) + q scale ----------------
__global__ __launch_bounds__(256) void rotary_kernel(u16* __restrict__ qkv) {
    int idx = blockIdx.x * 256 + threadIdx.x;       // B*N*H*32 = 4194304
    int i  = idx & 31;
    int hh = (idx >> 5) & 15;
    int n  = (idx >> 9) & (NSEQ - 1);
    int b  = idx >> 21;
    float inv = expf(-(float)i * 0.28782313663f);   // ln(10000)/32
    float f = (float)n * inv;
    float sn, cs;
    sincosf(f, &sn, &cs);
    size_t base = ((size_t)(b * NSEQ + n)) * QKV_N;
    size_t iq = base + hh * 64 + i;                 // q, scaled by DH^-0.5
    float q0 = bf2f(qkv[iq]), q1 = bf2f(qkv[iq + 32]);
    qkv[iq]      = f2bf((q0 * cs - q1 * sn) * 0.125f);
    qkv[iq + 32] = f2bf((q1 * cs + q0 * sn) * 0.125f);
    size_t ik = base + DIM + hh * 64 + i;           // k
    float k0 = bf2f(qkv[ik]), k1 = bf2f(qkv[ik + 32]);
    qkv[ik]      = f2bf(k0 * cs - k1 * sn);
    qkv[ik + 32] = f2bf(k1 * cs + k0 * sn);
}

// ---------------- windowed causal attention: one wave per query ----------------
__global__ __launch_bounds__(256) void attn_kernel(const u16* __restrict__ qkv,
                                                   u16* __restrict__ o) {
    __shared__ float q_lds[4][64];
    __shared__ float p_lds[4][2 * WIN];
    int wave = threadIdx.x >> 6, lane = threadIdx.x & 63;
    int q_lin = blockIdx.x * 4 + wave;              // 0 .. B*H*N-1
    int n  = q_lin & (NSEQ - 1);
    int hh = (q_lin >> 12) & 15;
    int b  = q_lin >> 16;
    int w0 = n >> 9;                                 // window index
    int qi = n & (WIN - 1);                          // pos within window
    size_t rowbase = (size_t)(b * NSEQ + n) * QKV_N;
    q_lds[wave][lane] = bf2f(qkv[rowbase + hh * 64 + lane]);
    __syncthreads();
    const float* qv = q_lds[wave];
    float sv[16];
    float m = -1e30f;
#pragma unroll
    for (int t = 0; t < 16; t++) {
        int j = lane + 64 * t;                       // key slot 0..1023
        bool cur = (j >= WIN);
        bool valid = cur ? ((j - WIN) <= qi) : (w0 > 0);
        float s = -1e30f;
        if (valid) {
            int kp = cur ? (w0 * WIN + j - WIN) : ((w0 - 1) * WIN + j);
            const u16* kr = qkv + (size_t)(b * NSEQ + kp) * QKV_N + DIM + hh * 64;
            float acc = 0.f;
#pragma unroll
            for (int d0 = 0; d0 < 64; d0 += 8) {
                union { uint4 u; u16 us[8]; } ld;
                ld.u = *(const uint4*)(kr + d0);
#pragma unroll
                for (int e = 0; e < 8; e++) acc += qv[d0 + e] * bf2f(ld.us[e]);
            }
            s = acc;
        }
        sv[t] = s;
        m = fmaxf(m, s);
    }
#pragma unroll
    for (int off = 32; off; off >>= 1) m = fmaxf(m, __shfl_xor(m, off));
    float l = 0.f;
#pragma unroll
    for (int t = 0; t < 16; t++) {
        float e = (sv[t] > -1e29f) ? expf(sv[t] - m) : 0.f;
        sv[t] = e; l += e;
    }
#pragma unroll
    for (int off = 32; off; off >>= 1) l += __shfl_xor(l, off);
    float linv = 1.f / l;
#pragma unroll
    for (int t = 0; t < 16; t++) p_lds[wave][lane + 64 * t] = sv[t] * linv;
    __syncthreads();
    // PV: lane = output dim, coalesced V reads, p broadcast from LDS
    int j_lo = (w0 > 0) ? 0 : WIN;
    int j_hi = WIN + qi;
    float acc = 0.f;
    for (int j = j_lo; j <= j_hi; j++) {
        float p = p_lds[wave][j];
        int kp = (j >= WIN) ? (w0 * WIN + j - WIN) : ((w0 - 1) * WIN + j);
        acc += p * bf2f(qkv[(size_t)(b * NSEQ + kp) * QKV_N + 2 * DIM + hh * 64 + lane]);
    }
    o[(size_t)(b * NSEQ + n) * DIM + hh * 64 + lane] = f2bf(acc);
}

// ---------------- GEGLU gate: ag = a * gelu_exact(g), bf16 ----------------
__global__ __launch_bounds__(256) void geglu_kernel(const u16* __restrict__ u,
                                                    u16* __restrict__ ag) {
    int col = blockIdx.x * 256 + threadIdx.x;
    int row = blockIdx.y;
    if (col >= INNER) return;
    float a = bf2f(u[(size_t)row * FF1_N + col]);
    float g = bf2f(u[(size_t)row * FF1_N + INNER + col]);
    float ge = 0.5f * g * (1.f + erff(g * 0.70710678118f));
    ag[(size_t)row * INNER + col] = f2bf(a * ge);
}

// ---------------- launch ----------------
extern "C" void kernel_launch(void* const* d_in, const int* in_sizes, int n_in,
                              void* d_out, int out_size, void* d_ws, size_t ws_size,
                              hipStream_t stream) {
    const float* x      = (const float*)d_in[0];
    const float* ln1_w  = (const float*)d_in[1];
    const float* ln1_b  = (const float*)d_in[2];
    const float* w_qkv  = (const float*)d_in[3];
    const float* w_out  = (const float*)d_in[4];
    const float* ln2_w  = (const float*)d_in[5];
    const float* w_ff1  = (const float*)d_in[6];
    const float* w_ff2  = (const float*)d_in[7];
    float* out = (float*)d_out;

    // element counts
    const int n_wq  = DIM * QKV_N;      // 3,145,728
    const int n_wo  = DIM * DIM;        // 1,048,576
    const int n_wf1 = DIM * FF1_N;      // 5,591,040
    const int n_wf2 = INNER * DIM;      // 2,795,520

    // workspace layout (bytes)
    char* ws = (char*)d_ws;
    size_t off = 0;
    auto alloc = [&](size_t bytes) { size_t o = off; off += (bytes + 255) & ~(size_t)255; return o; };
    size_t off_wq  = alloc((size_t)n_wq  * 2);
    size_t off_wo  = alloc((size_t)n_wo  * 2);
    size_t off_wf1 = alloc((size_t)n_wf1 * 2);
    size_t off_wf2 = alloc((size_t)n_wf2 * 2);
    size_t off_h   = alloc((size_t)ROWS * DIM * 2);        // h / h2 (bf16)
    size_t off_r1  = alloc((size_t)ROWS * FF1_N * 2);      // region: qkv+o, later u
    size_t off_x1  = alloc((size_t)ROWS * DIM * 4);        // x1 fp32
    size_t off_ag  = alloc((size_t)ROWS * INNER * 2);      // ag bf16
    u16* wq  = (u16*)(ws + off_wq);
    u16* wo  = (u16*)(ws + off_wo);
    u16* wf1 = (u16*)(ws + off_wf1);
    u16* wf2 = (u16*)(ws + off_wf2);
    u16* h   = (u16*)(ws + off_h);
    u16* qkv = (u16*)(ws + off_r1);
    u16* o   = (u16*)(ws + off_r1 + (size_t)ROWS * QKV_N * 2);  // inside r1, after qkv
    u16* u   = (u16*)(ws + off_r1);                             // reuses r1 after attn
    float* x1 = (float*)(ws + off_x1);
    u16* ag  = (u16*)(ws + off_ag);

    // 0) cast weights fp32 -> bf16
    f2b_kernel<<<(n_wq  + 255) / 256, 256, 0, stream>>>(w_qkv, wq,  n_wq);
    f2b_kernel<<<(n_wo  + 255) / 256, 256, 0, stream>>>(w_out, wo,  n_wo);
    f2b_kernel<<<(n_wf1 + 255) / 256, 256, 0, stream>>>(w_ff1, wf1, n_wf1);
    f2b_kernel<<<(n_wf2 + 255) / 256, 256, 0, stream>>>(w_ff2, wf2, n_wf2);

    // 1) LN1 (fp32 in, bf16 out)
    ln_kernel<<<ROWS, 256, 0, stream>>>(x, ln1_w, ln1_b, h);
    // 2) qkv = h @ wq   [8192 x 3072 x 1024], bf16 out
    {
        int tiles = (ROWS / 16) * (QKV_N / 16);
        gemm_kernel<false><<<tiles / 4, 256, 0, stream>>>(h, wq, nullptr, qkv, ROWS, QKV_N, DIM);
    }
    // 3) rotary + q scale, in-place
    rotary_kernel<<<(BATCH * NSEQ * HEADS * 32) / 256, 256, 0, stream>>>(qkv);
    // 4) attention -> o (bf16)
    attn_kernel<<<(BATCH * HEADS * NSEQ) / 4, 256, 0, stream>>>(qkv, o);
    // 5) x1 = o @ wo + x   [8192 x 1024 x 1024], fp32 out + fp32 resid
    {
        int tiles = (ROWS / 16) * (DIM / 16);
        gemm_kernel<true><<<tiles / 4, 256, 0, stream>>>(o, wo, x, x1, ROWS, DIM, DIM);
    }
    // 6) h2 = LN2(x1), gamma only (reuse h)
    ln_kernel<<<ROWS, 256, 0, stream>>>(x1, ln2_w, nullptr, h);
    // 7) u = h2 @ wf1   [8192 x 5460 x 1024], bf16 out (r1 region, qkv/o dead)
    {
        int tiles_n = (FF1_N + 15) / 16;                   // 342
        int tiles = (ROWS / 16) * tiles_n;                 // 175104, /4 exact
        gemm_kernel<false><<<tiles / 4, 256, 0, stream>>>(h, wf1, nullptr, u, ROWS, FF1_N, DIM);
    }
    // 8) ag = a * gelu(g)
    {
        dim3 grid((INNER + 255) / 256, ROWS);
        geglu_kernel<<<grid, 256, 0, stream>>>(u, ag);
    }
    // 9) out = ag @ wf2 + x1   [8192 x 1024 x 2730], fp32 out + fp32 resid
    {
        int tiles = (ROWS / 16) * (DIM / 16);
        gemm_kernel<true><<<tiles / 4, 256, 0, stream>>>(ag, wf2, x1, out, ROWS, DIM, INNER);
    }
    (void)in_sizes; (void)n_in; (void)out_size; (void)ws_size;
}

// Round 3
// 789.260 us; speedup vs baseline: 8.2450x; 8.2450x over previous
//
#include <hip/hip_runtime.h>
#include <stdint.h>

typedef unsigned short u16;
typedef unsigned int u32;

// ---------------- constants ----------------
#define BATCH 2
#define NSEQ  4096
#define DIM   1024
#define HEADS 16
#define DH    64
#define WIN   512
#define INNER 2730
#define ROWS  8192
#define QKV_N 3072
#define FF1_N 5460
#define FF1_NP 5504      // padded N for ff1 (43*128)
#define INNER_P 2752     // padded K for ff2 (86*32)

typedef __attribute__((ext_vector_type(8))) short short8;
typedef __attribute__((ext_vector_type(4))) float float4v;

__device__ __forceinline__ float bf2f(u16 u){ union{u32 i;float f;}c; c.i=((u32)u)<<16; return c.f; }
__device__ __forceinline__ u16 f2bf(float f){ union{float f;u32 i;}c; c.f=f; u32 i=c.i;
    return (u16)((i + 0x7FFFu + ((i>>16)&1u))>>16); }

// async global->LDS, 16B per lane. lds ptr must be wave-uniform base; HW places lane i at base+i*16.
__device__ __forceinline__ void gl_lds16(const u16* g, const u16* ldsbase) {
    __builtin_amdgcn_global_load_lds(
        (const __attribute__((address_space(1))) u32*)(uintptr_t)g,
        (__attribute__((address_space(3))) u32*)(uintptr_t)ldsbase,
        16, 0, 0);
}

// ---------------- weight transpose + cast: wt[n][k] = bf16(w[k][n]), zero-padded ----------------
__global__ __launch_bounds__(256) void wtrans_kernel(const float* __restrict__ w, u16* __restrict__ wt,
                                                     int K0, int N0, int K1, int N1) {
    __shared__ float tile[32][33];
    int kt = blockIdx.x, nt = blockIdx.y;
    int tx = threadIdx.x & 31, ty = threadIdx.x >> 5;   // ty 0..7
#pragma unroll
    for (int yy = 0; yy < 4; yy++) {
        int k = kt*32 + ty + yy*8, n = nt*32 + tx;
        tile[ty+yy*8][tx] = (k < K0 && n < N0) ? w[(size_t)k*N0 + n] : 0.f;
    }
    __syncthreads();
#pragma unroll
    for (int yy = 0; yy < 4; yy++) {
        int n = nt*32 + ty + yy*8, k = kt*32 + tx;
        if (n < N1 && k < K1) wt[(size_t)n*K1 + k] = f2bf(tile[tx][ty+yy*8]);
    }
}

// ---------------- LayerNorm: fp32 in, bf16 out (dim = 1024) ----------------
__global__ __launch_bounds__(256) void ln_kernel(const float* __restrict__ x,
                                                 const float* __restrict__ w,
                                                 const float* __restrict__ b,
                                                 u16* __restrict__ out) {
    int row = blockIdx.x;
    const float* xr = x + (size_t)row * DIM;
    int t = threadIdx.x;
    float v[4];
    float s = 0.f, s2 = 0.f;
#pragma unroll
    for (int i = 0; i < 4; i++) {
        float f = xr[t + 256 * i];
        v[i] = f; s += f; s2 += f * f;
    }
#pragma unroll
    for (int off = 32; off; off >>= 1) { s += __shfl_xor(s, off); s2 += __shfl_xor(s2, off); }
    __shared__ float ls[10];
    int wave = t >> 6, lane = t & 63;
    if (lane == 0) { ls[wave] = s; ls[4 + wave] = s2; }
    __syncthreads();
    if (t == 0) {
        float ts  = ls[0] + ls[1] + ls[2] + ls[3];
        float ts2 = ls[4] + ls[5] + ls[6] + ls[7];
        float mean = ts * (1.f / DIM);
        float var  = ts2 * (1.f / DIM) - mean * mean;
        ls[8] = mean; ls[9] = 1.f / sqrtf(var + 1e-5f);
    }
    __syncthreads();
    float mean = ls[8], inv = ls[9];
    u16* orow = out + (size_t)row * DIM;
#pragma unroll
    for (int i = 0; i < 4; i++) {
        int c = t + 256 * i;
        float y = (v[i] - mean) * inv * w[c];
        if (b) y += b[c];
        orow[c] = f2bf(y);
    }
}

// ---------------- m97-style GEMM: C[M,N] = A[M,K] @ Bt[N,K]^T (+fp32 resid) ----------------
// 128x128 block tile, BK=32, global_load_lds staging, 4 waves x (4x4) 16x16 MFMA tiles.
// Requires: M%128==0, N%128==0, K%32==0.
template <bool F32OUT>
__global__ __launch_bounds__(256) void gemm_tile(const u16* __restrict__ A,
                                                 const u16* __restrict__ Bt,
                                                 const float* __restrict__ resid,
                                                 void* __restrict__ Cv,
                                                 int M, int N, int K) {
    __shared__ u16 As[128 * 32];   // [m][k] row-major, rows of 64B
    __shared__ u16 Bs[128 * 32];   // [n][k] row-major
    int tiles_n = N >> 7;
    int tm = blockIdx.x / tiles_n, tn = blockIdx.x % tiles_n;
    int tid = threadIdx.x, wave = tid >> 6, lane = tid & 63;
    int quad = lane >> 4, l15 = lane & 15;
    int wm = wave >> 1, wn = wave & 1;
    int srow = wave * 32 + (lane >> 2);        // staging row (s=0)
    int scol = (lane & 3) * 8;                 // staging col (halves)
    const u16* Ag = A  + (size_t)(tm * 128 + srow) * K + scol;
    const u16* Bg = Bt + (size_t)(tn * 128 + srow) * K + scol;
    const u16* Alb = &As[wave * 1024];         // wave-uniform LDS bases
    const u16* Blb = &Bs[wave * 1024];
    float4v acc[4][4];
#pragma unroll
    for (int i = 0; i < 4; i++)
#pragma unroll
        for (int j = 0; j < 4; j++) acc[i][j] = (float4v){0.f, 0.f, 0.f, 0.f};
    for (int k0 = 0; k0 < K; k0 += 32) {
        __syncthreads();
        gl_lds16(Ag + k0,                 Alb);
        gl_lds16(Ag + (size_t)16*K + k0,  Alb + 512);
        gl_lds16(Bg + k0,                 Blb);
        gl_lds16(Bg + (size_t)16*K + k0,  Blb + 512);
        __syncthreads();
        short8 af[4], bf[4];
#pragma unroll
        for (int i = 0; i < 4; i++) af[i] = *(const short8*)&As[(wm*64 + i*16 + l15)*32 + quad*8];
#pragma unroll
        for (int j = 0; j < 4; j++) bf[j] = *(const short8*)&Bs[(wn*64 + j*16 + l15)*32 + quad*8];
#pragma unroll
        for (int i = 0; i < 4; i++)
#pragma unroll
            for (int j = 0; j < 4; j++)
                acc[i][j] = __builtin_amdgcn_mfma_f32_16x16x32_bf16(af[i], bf[j], acc[i][j], 0, 0, 0);
    }
#pragma unroll
    for (int i = 0; i < 4; i++) {
#pragma unroll
        for (int r = 0; r < 4; r++) {
            size_t row = (size_t)(tm*128 + wm*64 + i*16 + quad*4 + r);
#pragma unroll
            for (int j = 0; j < 4; j++) {
                int col = tn*128 + wn*64 + j*16 + l15;
                size_t idx = row * N + col;
                float v = acc[i][j][r];
                if (F32OUT) { if (resid) v += resid[idx]; ((float*)Cv)[idx] = v; }
                else ((u16*)Cv)[idx] = f2bf(v);
            }
        }
    }
}

// ---------------- rotary (in-place on bf16 qkv) + q scale ----------------
__global__ __launch_bounds__(256) void rotary_kernel(u16* __restrict__ qkv) {
    int idx = blockIdx.x * 256 + threadIdx.x;       // B*N*H*32
    int i  = idx & 31;
    int hh = (idx >> 5) & 15;
    int n  = (idx >> 9) & (NSEQ - 1);
    int b  = idx >> 21;
    float inv = expf(-(float)i * 0.28782313663f);   // ln(10000)/32
    float f = (float)n * inv;
    float sn, cs;
    sincosf(f, &sn, &cs);
    size_t base = ((size_t)(b * NSEQ + n)) * QKV_N;
    size_t iq = base + hh * 64 + i;
    float q0 = bf2f(qkv[iq]), q1 = bf2f(qkv[iq + 32]);
    qkv[iq]      = f2bf((q0 * cs - q1 * sn) * 0.125f);
    qkv[iq + 32] = f2bf((q1 * cs + q0 * sn) * 0.125f);
    size_t ik = base + DIM + hh * 64 + i;
    float k0 = bf2f(qkv[ik]), k1 = bf2f(qkv[ik + 32]);
    qkv[ik]      = f2bf(k0 * cs - k1 * sn);
    qkv[ik + 32] = f2bf(k1 * cs + k0 * sn);
}

// ---------------- V transpose: vt[b][h][d][n] = qkv.v[b,n,h,d] ----------------
__global__ __launch_bounds__(256) void vtrans_kernel(const u16* __restrict__ qkv, u16* __restrict__ vt) {
    __shared__ u16 tile[64][72];                    // row stride 144B (16B-mult)
    int t = threadIdx.x;
    int n0 = (blockIdx.x & 63) * 64;
    int hh = (blockIdx.x >> 6) & 15;
    int b  = blockIdx.x >> 10;
    int r = t >> 2, cb = (t & 3) * 16;
    const u16* src = qkv + (size_t)(b * NSEQ + n0 + r) * QKV_N + 2 * DIM + hh * 64 + cb;
    uint4 v0 = *(const uint4*)(src);
    uint4 v1 = *(const uint4*)(src + 8);
    *(uint4*)&tile[r][cb]     = v0;
    *(uint4*)&tile[r][cb + 8] = v1;
    __syncthreads();
    int d = t >> 2, nb = (t & 3) * 16;
    __align__(16) u16 vals[16];
#pragma unroll
    for (int e = 0; e < 16; e++) vals[e] = tile[nb + e][d];
    u16* dst = vt + ((size_t)(b * HEADS + hh) * DH + d) * NSEQ + n0 + nb;
    *(uint4*)(dst)     = *(uint4*)&vals[0];
    *(uint4*)(dst + 8) = *(uint4*)&vals[8];
}

// ---------------- MFMA flash attention: one wave per 16-query tile ----------------
__global__ __launch_bounds__(256) void attn_kernel(const u16* __restrict__ qkv,
                                                   const u16* __restrict__ vt,
                                                   u16* __restrict__ o) {
    __shared__ u16 p_lds[4][16][40];               // per-wave P tile, row stride 80B
    int tid = threadIdx.x, wave = tid >> 6, lane = tid & 63;
    int quad = lane >> 4, l15 = lane & 15;
    int bq = blockIdx.x & 7;
    int w0 = (blockIdx.x >> 3) & 7;
    int hh = (blockIdx.x >> 6) & 15;
    int b  = blockIdx.x >> 10;
    int qt = bq * 4 + wave;                        // q-tile 0..31 within window
    // Q A-fragments (q pre-scaled+rotated)
    const u16* qp = qkv + (size_t)(b*NSEQ + w0*WIN + qt*16 + l15) * QKV_N + hh*64 + quad*8;
    short8 aq0 = *(const short8*)(qp);
    short8 aq1 = *(const short8*)(qp + 32);
    float m_[4] = {-1e30f, -1e30f, -1e30f, -1e30f};
    float l_[4] = {0.f, 0.f, 0.f, 0.f};
    float4v O0 = {0,0,0,0}, O1 = {0,0,0,0}, O2 = {0,0,0,0}, O3 = {0,0,0,0};
    int cstart = (w0 == 0) ? 16 : 0;               // combined key chunks of 32: [0,512)=prev, [512,1024)=cur
    int clast  = 16 + (qt >> 1);
    int krow0 = b * NSEQ + (w0 - 1) * WIN;         // global row of combined key j
    const u16* vth = vt + (size_t)(b * HEADS + hh) * DH * NSEQ;
    for (int c = cstart; c <= clast; c++) {
        // ---- QK^T (two 16-key halves) ----
        float4v s0 = {0,0,0,0}, s1 = {0,0,0,0};
        {
            int j0 = c * 32 + l15;
            const u16* k0p = qkv + (size_t)(krow0 + j0)      * QKV_N + DIM + hh*64 + quad*8;
            const u16* k1p = qkv + (size_t)(krow0 + j0 + 16) * QKV_N + DIM + hh*64 + quad*8;
            short8 b00 = *(const short8*)(k0p);
            short8 b01 = *(const short8*)(k0p + 32);
            short8 b10 = *(const short8*)(k1p);
            short8 b11 = *(const short8*)(k1p + 32);
            s0 = __builtin_amdgcn_mfma_f32_16x16x32_bf16(aq0, b00, s0, 0, 0, 0);
            s0 = __builtin_amdgcn_mfma_f32_16x16x32_bf16(aq1, b01, s0, 0, 0, 0);
            s1 = __builtin_amdgcn_mfma_f32_16x16x32_bf16(aq0, b10, s1, 0, 0, 0);
            s1 = __builtin_amdgcn_mfma_f32_16x16x32_bf16(aq1, b11, s1, 0, 0, 0);
        }
        // ---- causal mask (only last chunk can contain future keys) ----
        if (c == clast) {
            int j0 = c * 32 + l15 - 512;           // within-window key index, half 0
            int qw = qt * 16 + quad * 4;
#pragma unroll
            for (int r = 0; r < 4; r++) {
                if (j0      > qw + r) s0[r] = -1e30f;
                if (j0 + 16 > qw + r) s1[r] = -1e30f;
            }
        }
        // ---- online softmax update ----
        float al[4];
#pragma unroll
        for (int r = 0; r < 4; r++) {
            float t = fmaxf(s0[r], s1[r]);
            t = fmaxf(t, __shfl_xor(t, 1)); t = fmaxf(t, __shfl_xor(t, 2));
            t = fmaxf(t, __shfl_xor(t, 4)); t = fmaxf(t, __shfl_xor(t, 8));
            float mn = fmaxf(m_[r], t);
            al[r] = __expf(m_[r] - mn);
            float p0 = __expf(s0[r] - mn), p1 = __expf(s1[r] - mn);
            s0[r] = p0; s1[r] = p1;
            float su = p0 + p1;
            su += __shfl_xor(su, 1); su += __shfl_xor(su, 2);
            su += __shfl_xor(su, 4); su += __shfl_xor(su, 8);
            l_[r] = l_[r] * al[r] + su;
            m_[r] = mn;
        }
        // ---- P: C-layout -> A-layout via per-wave LDS ----
#pragma unroll
        for (int r = 0; r < 4; r++) {
            p_lds[wave][quad*4 + r][l15]      = f2bf(s0[r]);
            p_lds[wave][quad*4 + r][16 + l15] = f2bf(s1[r]);
        }
#pragma unroll
        for (int r = 0; r < 4; r++) { O0[r] *= al[r]; O1[r] *= al[r]; O2[r] *= al[r]; O3[r] *= al[r]; }
        short8 pf = *(const short8*)&p_lds[wave][l15][quad*8];
        // ---- PV: B-frags from transposed V (contiguous 16B) ----
        {
            const u16* vp = vth + (size_t)l15 * NSEQ + ((w0 - 1) * WIN + c * 32 + quad * 8);
            short8 v0 = *(const short8*)(vp);
            short8 v1 = *(const short8*)(vp + 16 * NSEQ);
            short8 v2 = *(const short8*)(vp + 32 * NSEQ);
            short8 v3 = *(const short8*)(vp + 48 * NSEQ);
            O0 = __builtin_amdgcn_mfma_f32_16x16x32_bf16(pf, v0, O0, 0, 0, 0);
            O1 = __builtin_amdgcn_mfma_f32_16x16x32_bf16(pf, v1, O1, 0, 0, 0);
            O2 = __builtin_amdgcn_mfma_f32_16x16x32_bf16(pf, v2, O2, 0, 0, 0);
            O3 = __builtin_amdgcn_mfma_f32_16x16x32_bf16(pf, v3, O3, 0, 0, 0);
        }
    }
    // ---- epilogue: O /= l ----
#pragma unroll
    for (int r = 0; r < 4; r++) {
        float inv = 1.f / l_[r];
        size_t base = (size_t)(b*NSEQ + w0*WIN + qt*16 + quad*4 + r) * DIM + hh*64 + l15;
        o[base]      = f2bf(O0[r] * inv);
        o[base + 16] = f2bf(O1[r] * inv);
        o[base + 32] = f2bf(O2[r] * inv);
        o[base + 48] = f2bf(O3[r] * inv);
    }
}

// ---------------- GEGLU gate (padded strides) ----------------
__global__ __launch_bounds__(256) void geglu_kernel(const u16* __restrict__ u, u16* __restrict__ ag) {
    int col = blockIdx.x * 256 + threadIdx.x;
    int row = blockIdx.y;
    if (col >= INNER_P) return;
    float v = 0.f;
    if (col < INNER) {
        float a = bf2f(u[(size_t)row * FF1_NP + col]);
        float g = bf2f(u[(size_t)row * FF1_NP + INNER + col]);
        v = a * 0.5f * g * (1.f + erff(g * 0.70710678118f));
    }
    ag[(size_t)row * INNER_P + col] = f2bf(v);
}

// ---------------- launch ----------------
extern "C" void kernel_launch(void* const* d_in, const int* in_sizes, int n_in,
                              void* d_out, int out_size, void* d_ws, size_t ws_size,
                              hipStream_t stream) {
    const float* x      = (const float*)d_in[0];
    const float* ln1_w  = (const float*)d_in[1];
    const float* ln1_b  = (const float*)d_in[2];
    const float* w_qkv  = (const float*)d_in[3];
    const float* w_out  = (const float*)d_in[4];
    const float* ln2_w  = (const float*)d_in[5];
    const float* w_ff1  = (const float*)d_in[6];
    const float* w_ff2  = (const float*)d_in[7];
    float* out = (float*)d_out;

    char* ws = (char*)d_ws;
    size_t off = 0;
    auto alloc = [&](size_t bytes) { size_t o = off; off += (bytes + 255) & ~(size_t)255; return o; };
    size_t off_wqt  = alloc((size_t)QKV_N  * DIM * 2);         // [3072][1024] bf16
    size_t off_wot  = alloc((size_t)DIM    * DIM * 2);         // [1024][1024]
    size_t off_wf1t = alloc((size_t)FF1_NP * DIM * 2);         // [5504][1024]
    size_t off_wf2t = alloc((size_t)DIM    * INNER_P * 2);     // [1024][2752]
    size_t off_h    = alloc((size_t)ROWS * DIM * 2);           // bf16 h / h2
    size_t sz_qkv = (size_t)ROWS * QKV_N * 2;                  // 50.3MB
    size_t sz_vt  = (size_t)BATCH * HEADS * DH * NSEQ * 2;     // 16.8MB
    size_t sz_o   = (size_t)ROWS * DIM * 2;                    // 16.8MB
    size_t sz_u   = (size_t)ROWS * FF1_NP * 2;                 // 90.2MB
    size_t r1sz = sz_qkv + sz_vt + sz_o; if (sz_u > r1sz) r1sz = sz_u;
    size_t off_r1   = alloc(r1sz);
    size_t off_x1   = alloc((size_t)ROWS * DIM * 4);           // fp32
    size_t off_ag   = alloc((size_t)ROWS * INNER_P * 2);       // bf16

    u16* wqt  = (u16*)(ws + off_wqt);
    u16* wot  = (u16*)(ws + off_wot);
    u16* wf1t = (u16*)(ws + off_wf1t);
    u16* wf2t = (u16*)(ws + off_wf2t);
    u16* h    = (u16*)(ws + off_h);
    u16* qkv  = (u16*)(ws + off_r1);
    u16* vt   = (u16*)(ws + off_r1 + sz_qkv);
    u16* o    = (u16*)(ws + off_r1 + sz_qkv + sz_vt);
    u16* u    = (u16*)(ws + off_r1);                           // reuses region after attn block
    float* x1 = (float*)(ws + off_x1);
    u16* ag   = (u16*)(ws + off_ag);

    // 0) transpose+cast weights -> bf16 [N][K] (zero-padded)
    wtrans_kernel<<<dim3(32, 96),  256, 0, stream>>>(w_qkv, wqt,  DIM,   QKV_N, DIM,     QKV_N);
    wtrans_kernel<<<dim3(32, 32),  256, 0, stream>>>(w_out, wot,  DIM,   DIM,   DIM,     DIM);
    wtrans_kernel<<<dim3(32, 172), 256, 0, stream>>>(w_ff1, wf1t, DIM,   FF1_N, DIM,     FF1_NP);
    wtrans_kernel<<<dim3(86, 32),  256, 0, stream>>>(w_ff2, wf2t, INNER, DIM,   INNER_P, DIM);

    // 1) LN1
    ln_kernel<<<ROWS, 256, 0, stream>>>(x, ln1_w, ln1_b, h);
    // 2) qkv = h @ w_qkv
    gemm_tile<false><<<(ROWS/128) * (QKV_N/128), 256, 0, stream>>>(h, wqt, nullptr, qkv, ROWS, QKV_N, DIM);
    // 3) rotary + q scale
    rotary_kernel<<<(BATCH * NSEQ * HEADS * 32) / 256, 256, 0, stream>>>(qkv);
    // 4) V transpose
    vtrans_kernel<<<BATCH * HEADS * (NSEQ / 64), 256, 0, stream>>>(qkv, vt);
    // 5) attention
    attn_kernel<<<BATCH * HEADS * 8 * 8, 256, 0, stream>>>(qkv, vt, o);
    // 6) x1 = o @ w_out + x
    gemm_tile<true><<<(ROWS/128) * (DIM/128), 256, 0, stream>>>(o, wot, x, x1, ROWS, DIM, DIM);
    // 7) h2 = LN2(x1)
    ln_kernel<<<ROWS, 256, 0, stream>>>(x1, ln2_w, nullptr, h);
    // 8) u = h2 @ w_ff1 (N padded to 5504)
    gemm_tile<false><<<(ROWS/128) * (FF1_NP/128), 256, 0, stream>>>(h, wf1t, nullptr, u, ROWS, FF1_NP, DIM);
    // 9) ag = a * gelu(g) (K padded to 2752, zero-filled)
    geglu_kernel<<<dim3((INNER_P + 255) / 256, ROWS), 256, 0, stream>>>(u, ag);
    // 10) out = ag @ w_ff2 + x1
    gemm_tile<true><<<(ROWS/128) * (DIM/128), 256, 0, stream>>>(ag, wf2t, x1, out, ROWS, DIM, INNER_P);

    (void)in_sizes; (void)n_in; (void)out_size; (void)ws_size;
}